// Round 6
// baseline (339.937 us; speedup 1.0000x reference)
//
#include <hip/hip_runtime.h>
#include <hip/hip_bf16.h>

typedef __hip_bfloat16 bf16;
typedef __attribute__((ext_vector_type(8))) short bf16x8;  // 8 bf16 in 4 VGPRs
typedef __attribute__((ext_vector_type(4))) float f32x4;

#define SEQ_LEN 2048
#define K_MAX   32
#define D_SPEC  256
#define D_MODEL 768
#define N_LAYERS 4
#define BATCH   2
#define MTOT    (BATCH * SEQ_LEN)       // 4096 rows (b*2048+t)
#define NU      (D_SPEC * K_MAX * 2)    // 16384 cols; n = (ok>>4)*32 + ri*16 + (ok&15)
#define NCOND   (2 * D_MODEL)           // 1536
#define NCHUNK  32

__device__ inline float b2f(bf16 h) { return __bfloat162float(h); }

__device__ inline void gload16(const void* gp, void* lp) {
  __builtin_amdgcn_global_load_lds((const __attribute__((address_space(1))) void*)gp,
                                   (__attribute__((address_space(3))) void*)lp, 16, 0, 0);
}

// LDS XOR swizzle (kept from R5 — neutral; conflicts proved to be on the staging-write side).
__device__ inline int stage_c16(int lane) { return ((lane & 3) ^ ((lane >> 2) & 3) ^ ((lane >> 4) & 3)); }
__device__ inline int frag_off(int R, int q) {
  return (R << 5) + (((q ^ (R & 3) ^ ((R >> 2) & 3)) & 3) << 3);
}

// ---------------------------------------------------------------------------
// prep: Bmat (B^T, interleaved re/im groups), bf16 casts, twiddle table.
// ---------------------------------------------------------------------------
__global__ void prep(const bf16* __restrict__ conv_w, const float* __restrict__ w_shared,
                     const float* __restrict__ layer_w,
                     bf16* __restrict__ Bmat, bf16* __restrict__ wsb, bf16* __restrict__ lwb,
                     float2* __restrict__ twtab) {
  int idx = blockIdx.x * blockDim.x + threadIdx.x;
  int stride = gridDim.x * blockDim.x;
  for (int j = idx; j < NU * D_SPEC; j += stride) {
    int n = j >> 8, i = j & 255;
    int g = n >> 5, ri = (n >> 4) & 1, c = n & 15;
    int ok = (g << 4) + c, o = ok >> 5, k = ok & 31;
    Bmat[j] = conv_w[o * 16384 + i * 64 + k * 2 + ri];
  }
  for (int j = idx; j < D_MODEL * D_SPEC; j += stride) wsb[j] = __float2bfloat16(w_shared[j]);
  for (int j = idx; j < N_LAYERS * NCOND * D_MODEL; j += stride) lwb[j] = __float2bfloat16(layer_w[j]);
  for (int j = idx; j < SEQ_LEN * K_MAX; j += stride) {
    int t = j >> 5, k = j & 31;
    float ang = (-6.283185307179586f / 2048.0f) * (float)((t * k) & 2047);
    float s, c; sincosf(ang, &s, &c);
    twtab[j] = make_float2(c, s);
  }
}

// ---------------------------------------------------------------------------
// Shared GEMM core (128x128 tile, m97 pattern) producing acc[4][4] with x
// folded into the re-planes. Used by gemm_t and gemm_p.
// ---------------------------------------------------------------------------
#define GEMM_CORE(As, Bs, A, B, x)                                                       \
  const int tid = threadIdx.x;                                                           \
  const int wave = tid >> 6, lane = tid & 63;                                            \
  const int wm = (wave >> 1) << 6, wn = (wave & 1) << 6;                                 \
  const int lrow = lane & 15, quad = lane >> 4;                                          \
  const int m0 = blockIdx.y << 7, n0 = blockIdx.x << 7;                                  \
  f32x4 acc[4][4] = {};                                                                  \
  for (int k0 = 0; k0 < D_SPEC; k0 += 32) {                                              \
    _Pragma("unroll")                                                                    \
    for (int c = 0; c < 2; ++c) {                                                        \
      int rr = ((wave * 2 + c) << 4) + (lane >> 2);                                      \
      int cb = stage_c16(lane) << 4;                                                     \
      int lq = (((wave * 2 + c) << 6) + lane) << 4;                                      \
      gload16((const char*)A + (((size_t)(m0 + rr) * D_SPEC + k0) << 1) + cb, (char*)As + lq); \
      gload16((const char*)B + (((size_t)(n0 + rr) * D_SPEC + k0) << 1) + cb, (char*)Bs + lq); \
    }                                                                                    \
    __syncthreads();                                                                     \
    bf16x8 af[4], bfr[4];                                                                \
    _Pragma("unroll")                                                                    \
    for (int i = 0; i < 4; ++i) {                                                        \
      af[i]  = *(const bf16x8*)(As + frag_off(wm + (i << 4) + lrow, quad));              \
      bfr[i] = *(const bf16x8*)(Bs + frag_off(wn + (i << 4) + lrow, quad));              \
    }                                                                                    \
    _Pragma("unroll")                                                                    \
    for (int mt = 0; mt < 4; ++mt)                                                       \
      _Pragma("unroll")                                                                  \
      for (int nt = 0; nt < 4; ++nt)                                                     \
        acc[mt][nt] = __builtin_amdgcn_mfma_f32_16x16x32_bf16(af[mt], bfr[nt], acc[mt][nt], 0, 0, 0); \
    __syncthreads();                                                                     \
  }                                                                                      \
  const int mbase = m0 + wm;                 /* 64-row slab == exactly one chunk */      \
  const int b = mbase >> 11;                                                             \
  const int chunk = (mbase >> 6) & 31;                                                   \
  const int g0 = (n0 + wn) >> 5;             /* even */                                  \
  const int o = g0 >> 1;                     /* lane-uniform */                          \
  _Pragma("unroll")                                                                      \
  for (int mt = 0; mt < 4; ++mt)                                                         \
    _Pragma("unroll")                                                                    \
    for (int r = 0; r < 4; ++r) {                                                        \
      int m = mbase + (mt << 4) + (quad << 2) + r;                                       \
      float xv = b2f(x[((size_t)m << 8) + o]);                                           \
      acc[mt][0][r] += xv;                                                               \
      acc[mt][2][r] += xv;                                                               \
    }

// ---------------------------------------------------------------------------
// Pass 1: GEMM -> per-chunk complex totals only (raw, un-normed). No v store.
// ---------------------------------------------------------------------------
__global__ __launch_bounds__(256, 3) void gemm_t(
    const bf16* __restrict__ A, const bf16* __restrict__ B, const bf16* __restrict__ x,
    const float2* __restrict__ twtab, float* __restrict__ totals) {
  __shared__ bf16 As[128 * 32];
  __shared__ bf16 Bs[128 * 32];
  GEMM_CORE(As, Bs, A, B, x)

#pragma unroll
  for (int j = 0; j < 2; ++j) {
    const int k = lrow + (j << 4);
    const int ok = ((g0 + j) << 4) + lrow;
    float sumr = 0.f, sumi = 0.f;
#pragma unroll
    for (int mt = 0; mt < 4; ++mt) {
#pragma unroll
      for (int r = 0; r < 4; ++r) {
        int t = (mbase + (mt << 4) + (quad << 2) + r) & 2047;
        float2 tw = twtab[(t << 5) + k];
        float ur = acc[mt][2 * j][r], ui = acc[mt][2 * j + 1][r];
        sumr += tw.x * ur - tw.y * ui;
        sumi += tw.x * ui + tw.y * ur;
      }
    }
    sumr += __shfl_xor(sumr, 16, 64); sumr += __shfl_xor(sumr, 32, 64);
    sumi += __shfl_xor(sumi, 16, 64); sumi += __shfl_xor(sumi, 32, 64);
    if (quad == 0) {
      size_t tb = ((((size_t)(b * NCHUNK + chunk)) << 13) + ok) << 1;
      totals[tb] = sumr; totals[tb + 1] = sumi;
    }
  }
}

// In-place exclusive prefix over chunks for each of the 16384 chains (raw).
__global__ void tprefix(float* __restrict__ totals) {
  int id = blockIdx.x * blockDim.x + threadIdx.x;   // (b<<13) + ok
  int b = id >> 13, ok = id & 8191;
  float sr = 0.f, si = 0.f;
  for (int cc = 0; cc < NCHUNK; ++cc) {
    size_t idx = ((((size_t)(b * NCHUNK + cc)) << 13) + ok) << 1;
    float tr = totals[idx], ti = totals[idx + 1];
    totals[idx] = sr; totals[idx + 1] = si;
    sr += tr; si += ti;
  }
}

// ---------------------------------------------------------------------------
// Pass 2: GEMM -> full prefix (seeded with inter-chunk carry) -> modReLU
// magnitude -> mean over k -> pooled. Nothing else materialized.
// ---------------------------------------------------------------------------
__global__ __launch_bounds__(256, 3) void gemm_p(
    const bf16* __restrict__ A, const bf16* __restrict__ B, const bf16* __restrict__ x,
    const float2* __restrict__ twtab, const float* __restrict__ totals,
    const bf16* __restrict__ mrb, bf16* __restrict__ pooled) {
  __shared__ bf16 As[128 * 32];
  __shared__ bf16 Bs[128 * 32];
  GEMM_CORE(As, Bs, A, B, x)

  const float norm2 = 0.00048828125f;        // 1/2048
  const float biaso = b2f(mrb[o]);

  // seed intra-chunk carries with the inter-chunk exclusive base (raw)
  float carry_r[2], carry_i[2];
#pragma unroll
  for (int j = 0; j < 2; ++j) {
    const int ok = ((g0 + j) << 4) + lrow;
    size_t tb = ((((size_t)(b * NCHUNK + chunk)) << 13) + ok) << 1;
    carry_r[j] = totals[tb]; carry_i[j] = totals[tb + 1];
  }

#pragma unroll
  for (int mt = 0; mt < 4; ++mt) {
    float pr[2][4], pi[2][4];
#pragma unroll
    for (int j = 0; j < 2; ++j) {
      const int k = lrow + (j << 4);
      float vr[4], vi[4];
#pragma unroll
      for (int r = 0; r < 4; ++r) {
        int t = (mbase + (mt << 4) + (quad << 2) + r) & 2047;
        float2 tw = twtab[(t << 5) + k];
        float ur = acc[mt][2 * j][r], ui = acc[mt][2 * j + 1][r];
        vr[r] = tw.x * ur - tw.y * ui;
        vi[r] = tw.x * ui + tw.y * ur;
      }
      vr[1] += vr[0]; vr[2] += vr[1]; vr[3] += vr[2];
      vi[1] += vi[0]; vi[2] += vi[1]; vi[3] += vi[2];
      float Qr = vr[3], Qi = vi[3];
      float Tr = Qr, Ti = Qi;
      float tr = __shfl(Tr, lane - 16, 64), ti = __shfl(Ti, lane - 16, 64);
      if (quad >= 1) { Tr += tr; Ti += ti; }
      tr = __shfl(Tr, lane - 32, 64); ti = __shfl(Ti, lane - 32, 64);
      if (quad >= 2) { Tr += tr; Ti += ti; }
      float Er = Tr - Qr + carry_r[j], Ei = Ti - Qi + carry_i[j];
      float c3r = __shfl(Tr, 48 + lrow, 64), c3i = __shfl(Ti, 48 + lrow, 64);
      carry_r[j] += c3r; carry_i[j] += c3i;
#pragma unroll
      for (int r = 0; r < 4; ++r) { pr[j][r] = vr[r] + Er; pi[j][r] = vi[r] + Ei; }
    }
    // modReLU magnitude + sum over this lane's 2 chains, then over 16 lrow lanes
    float red[4];
#pragma unroll
    for (int r = 0; r < 4; ++r) {
      float nm = 0.f;
#pragma unroll
      for (int j = 0; j < 2; ++j) {
        float rr = pr[j][r] * pr[j][r] + pi[j][r] * pi[j][r];
        float he = __builtin_amdgcn_sqrtf(norm2 * rr + 1e-8f);
        nm += fmaxf(he - biaso, 0.f);
      }
      red[r] = nm;
    }
#pragma unroll
    for (int r = 0; r < 4; ++r) {
      red[r] += __shfl_xor(red[r], 1, 64);
      red[r] += __shfl_xor(red[r], 2, 64);
      red[r] += __shfl_xor(red[r], 4, 64);
      red[r] += __shfl_xor(red[r], 8, 64);
    }
    if (lrow == 0) {
#pragma unroll
      for (int r = 0; r < 4; ++r) {
        int m = mbase + (mt << 4) + (quad << 2) + r;
        pooled[((size_t)m << 8) + o] = __float2bfloat16(red[r] * (1.f / 32.f));
      }
    }
  }
}

// ---------------------------------------------------------------------------
// Plain GEMM for the two dense projections (swizzled LDS).
// EPI 1: +bias, SiLU, store bf16 ; EPI 2: +bias[z], store f32
// ---------------------------------------------------------------------------
template <int EPI>
__global__ __launch_bounds__(256, 2) void gemm_k(
    const bf16* __restrict__ A, const bf16* __restrict__ B, void* __restrict__ Cp,
    const float* __restrict__ bias, int N, int K,
    long long c_bstride, long long b_bstride, int bias_bstride) {
  __shared__ bf16 As[128 * 32];
  __shared__ bf16 Bs[128 * 32];
  const int tid = threadIdx.x;
  const int wave = tid >> 6, lane = tid & 63;
  const int wm = (wave >> 1) << 6, wn = (wave & 1) << 6;
  const int lrow = lane & 15, quad = lane >> 4;
  const int m0 = blockIdx.y << 7, n0 = blockIdx.x << 7;
  const int z = blockIdx.z;
  const bf16* Bz = B + (size_t)z * b_bstride;

  f32x4 acc[4][4] = {};

  for (int k0 = 0; k0 < K; k0 += 32) {
#pragma unroll
    for (int c = 0; c < 2; ++c) {
      int rr = ((wave * 2 + c) << 4) + (lane >> 2);
      int cb = stage_c16(lane) << 4;
      int lq = (((wave * 2 + c) << 6) + lane) << 4;
      gload16((const char*)A  + (((size_t)(m0 + rr) * K + k0) << 1) + cb, (char*)As + lq);
      gload16((const char*)Bz + (((size_t)(n0 + rr) * K + k0) << 1) + cb, (char*)Bs + lq);
    }
    __syncthreads();
    bf16x8 af[4], bfr[4];
#pragma unroll
    for (int i = 0; i < 4; ++i) {
      af[i]  = *(const bf16x8*)(As + frag_off(wm + (i << 4) + lrow, quad));
      bfr[i] = *(const bf16x8*)(Bs + frag_off(wn + (i << 4) + lrow, quad));
    }
#pragma unroll
    for (int mt = 0; mt < 4; ++mt)
#pragma unroll
      for (int nt = 0; nt < 4; ++nt)
        acc[mt][nt] = __builtin_amdgcn_mfma_f32_16x16x32_bf16(af[mt], bfr[nt], acc[mt][nt], 0, 0, 0);
    __syncthreads();
  }

#pragma unroll
  for (int mt = 0; mt < 4; ++mt) {
#pragma unroll
    for (int nt = 0; nt < 4; ++nt) {
#pragma unroll
      for (int r = 0; r < 4; ++r) {
        int gm = m0 + wm + (mt << 4) + (quad << 2) + r;
        int gn = n0 + wn + (nt << 4) + lrow;
        float v = acc[mt][nt][r];
        if (EPI == 1) {
          v += bias[gn];
          v = v / (1.f + __expf(-v));                    // SiLU
          ((bf16*)Cp)[(size_t)gm * N + gn] = __float2bfloat16(v);
        } else {
          v += bias[(size_t)z * bias_bstride + gn];
          ((float*)Cp)[(size_t)z * c_bstride + (size_t)gm * N + gn] = v;
        }
      }
    }
  }
}

// ---------------------------------------------------------------------------
extern "C" void kernel_launch(void* const* d_in, const int* in_sizes, int n_in,
                              void* d_out, int out_size, void* d_ws, size_t ws_size,
                              hipStream_t stream) {
  const bf16* x        = (const bf16*)d_in[0];
  const bf16* conv_w   = (const bf16*)d_in[1];
  const bf16* mrb      = (const bf16*)d_in[2];
  const float* w_shared = (const float*)d_in[3];
  const float* b_shared = (const float*)d_in[4];
  const float* layer_w  = (const float*)d_in[5];
  const float* layer_b  = (const float*)d_in[6];
  float* out = (float*)d_out;

  char* ws = (char*)d_ws;
  bf16* Bmat    = (bf16*)(ws);                // 16384*256*2 = 8,388,608
  float2* twtab = (float2*)(ws + 8388608);    // 524,288            -> 8,912,896
  float* totals = (float*)(ws + 8912896);     // 4,194,304          -> 13,107,200
  bf16* pooled  = (bf16*)(ws + 13107200);     // 2,097,152          -> 15,204,352
  bf16* wsb     = (bf16*)(ws + 15204352);     // 393,216            -> 15,597,568
  bf16* hidden  = (bf16*)(ws + 15597568);     // 6,291,456          -> 21,889,024
  bf16* lwb     = (bf16*)(ws + 21889024);     // 9,437,184          -> 31,326,208

  prep<<<2048, 256, 0, stream>>>(conv_w, w_shared, layer_w, Bmat, wsb, lwb, twtab);

  // pass 1: chunk totals (no v materialization)
  gemm_t<<<dim3(NU / 128, MTOT / 128, 1), 256, 0, stream>>>(x, Bmat, x, twtab, totals);

  tprefix<<<64, 256, 0, stream>>>(totals);

  // pass 2: recompute + prefix + modReLU + pool
  gemm_p<<<dim3(NU / 128, MTOT / 128, 1), 256, 0, stream>>>(x, Bmat, x, twtab, totals, mrb, pooled);

  // hidden = silu(pooled @ w_shared^T + b_shared)
  gemm_k<1><<<dim3(D_MODEL / 128, MTOT / 128, 1), 256, 0, stream>>>(
      pooled, wsb, hidden, b_shared, D_MODEL, D_SPEC, 0, 0, 0);

  // cond[l] = hidden @ layer_w[l]^T + layer_b[l]
  gemm_k<2><<<dim3(NCOND / 128, MTOT / 128, N_LAYERS), 256, 0, stream>>>(
      hidden, lwb, out, layer_b, NCOND, D_MODEL,
      (long long)MTOT * NCOND, (long long)NCOND * D_MODEL, NCOND);
}

// Round 7
// 325.406 us; speedup vs baseline: 1.0447x; 1.0447x over previous
//
#include <hip/hip_runtime.h>
#include <hip/hip_bf16.h>

typedef __hip_bfloat16 bf16;
typedef __attribute__((ext_vector_type(8))) short bf16x8;  // 8 bf16 in 4 VGPRs
typedef __attribute__((ext_vector_type(4))) float f32x4;

#define SEQ_LEN 2048
#define K_MAX   32
#define D_SPEC  256
#define D_MODEL 768
#define N_LAYERS 4
#define BATCH   2
#define MTOT    (BATCH * SEQ_LEN)       // 4096 rows (b*2048+t)
#define NU      (D_SPEC * K_MAX * 2)    // 16384 cols; n = (ok>>4)*32 + ri*16 + (ok&15)
#define NCOND   (2 * D_MODEL)           // 1536
#define NCHUNK  32

__device__ inline float b2f(bf16 h) { return __bfloat162float(h); }

__device__ inline void gload16(const void* gp, void* lp) {
  __builtin_amdgcn_global_load_lds((const __attribute__((address_space(1))) void*)gp,
                                   (__attribute__((address_space(3))) void*)lp, 16, 0, 0);
}

// LDS XOR swizzle (neutral but harmless; staging-side conflicts are structural).
__device__ inline int stage_c16(int lane) { return ((lane & 3) ^ ((lane >> 2) & 3) ^ ((lane >> 4) & 3)); }
__device__ inline int frag_off(int R, int q) {
  return (R << 5) + (((q ^ (R & 3) ^ ((R >> 2) & 3)) & 3) << 3);
}

// Full-rate DPP sum over each 16-lane row; result valid in lane 15 of each row.
__device__ inline float row_sum16(float v) {
  v += __int_as_float(__builtin_amdgcn_update_dpp(0, __float_as_int(v), 0x111, 0xF, 0xF, true)); // row_shr:1
  v += __int_as_float(__builtin_amdgcn_update_dpp(0, __float_as_int(v), 0x112, 0xF, 0xF, true)); // row_shr:2
  v += __int_as_float(__builtin_amdgcn_update_dpp(0, __float_as_int(v), 0x114, 0xF, 0xF, true)); // row_shr:4
  v += __int_as_float(__builtin_amdgcn_update_dpp(0, __float_as_int(v), 0x118, 0xF, 0xF, true)); // row_shr:8
  return v;
}

// ---------------------------------------------------------------------------
// prep: Bmat (B^T interleaved, for gemm_p), W2 ([k][o][2i] = [w_r|w_i] K'=512,
// for wtot), bf16 casts of w_shared/layer_w, twiddle table (for ybuild).
// ---------------------------------------------------------------------------
__global__ void prep(const bf16* __restrict__ conv_w, const float* __restrict__ w_shared,
                     const float* __restrict__ layer_w,
                     bf16* __restrict__ Bmat, bf16* __restrict__ W2,
                     bf16* __restrict__ wsb, bf16* __restrict__ lwb,
                     float2* __restrict__ twtab) {
  int idx = blockIdx.x * blockDim.x + threadIdx.x;
  int stride = gridDim.x * blockDim.x;
  for (int j = idx; j < NU * D_SPEC; j += stride) {
    int n = j >> 8, i = j & 255;
    int g = n >> 5, ri = (n >> 4) & 1, c = n & 15;
    int ok = (g << 4) + c, o = ok >> 5, k = ok & 31;
    Bmat[j] = conv_w[o * 16384 + i * 64 + k * 2 + ri];
  }
  for (int j = idx; j < K_MAX * D_SPEC * 512; j += stride) {
    int k = j >> 17, o = (j >> 9) & 255, i2 = j & 511;
    W2[j] = conv_w[o * 16384 + (i2 >> 1) * 64 + k * 2 + (i2 & 1)];
  }
  for (int j = idx; j < D_MODEL * D_SPEC; j += stride) wsb[j] = __float2bfloat16(w_shared[j]);
  for (int j = idx; j < N_LAYERS * NCOND * D_MODEL; j += stride) lwb[j] = __float2bfloat16(layer_w[j]);
  for (int j = idx; j < SEQ_LEN * K_MAX; j += stride) {
    int t = j >> 5, k = j & 31;
    float ang = (-6.283185307179586f / 2048.0f) * (float)((t * k) & 2047);
    float s, c; sincosf(ang, &s, &c);
    twtab[j] = make_float2(c, s);
  }
}

// ---------------------------------------------------------------------------
// ybuild: Y[b,c,k,i] = sum_{t in chunk} tw(t,k)*x[b,t,i], stored bf16 in the
// wtot B^T layout Y2[k][col][2i]: col=bc*2+comp; comp=r: (yc,-ys), comp=i: (ys,yc).
// Grid: 128 blocks = (bc 64) x (k-half 2). Thread = i.
// ---------------------------------------------------------------------------
__global__ __launch_bounds__(256) void ybuild(const bf16* __restrict__ x,
                                              const float2* __restrict__ twtab,
                                              bf16* __restrict__ Y2) {
  const int bx = blockIdx.x;
  const int bc = bx >> 1, kh = (bx & 1) << 4;   // k in [kh, kh+16)
  const int b = bc >> 5, c = bc & 31;
  const int t0 = c << 6;
  const int i = threadIdx.x;
  float accC[16] = {}, accS[16] = {};
  for (int t = 0; t < 64; ++t) {
    float xv = b2f(x[(((size_t)(b << 11) + t0 + t) << 8) + i]);
    const float2* twrow = twtab + ((t0 + t) << 5) + kh;
#pragma unroll
    for (int kk = 0; kk < 16; ++kk) {
      float2 tw = twrow[kk];
      accC[kk] += tw.x * xv;
      accS[kk] += tw.y * xv;
    }
  }
#pragma unroll
  for (int kk = 0; kk < 16; ++kk) {
    int k = kh + kk;
    __hip_bfloat162 p0, p1;
    p0.x = __float2bfloat16(accC[kk]); p0.y = __float2bfloat16(-accS[kk]);
    p1.x = __float2bfloat16(accS[kk]); p1.y = __float2bfloat16(accC[kk]);
    *(__hip_bfloat162*)(Y2 + (((size_t)(k << 7) + (bc << 1)) << 9) + (i << 1)) = p0;
    *(__hip_bfloat162*)(Y2 + (((size_t)(k << 7) + (bc << 1) + 1) << 9) + (i << 1)) = p1;
  }
}

// ---------------------------------------------------------------------------
// wtot: per-k complex GEMM totals[bc,o,k] = W[k] (256o x 512) @ Y2[k]^T (128col x 512)
// + self-term Y[bc,k,o]. Grid (1, 2, 32).
// ---------------------------------------------------------------------------
__global__ __launch_bounds__(256, 2) void wtot(const bf16* __restrict__ W2,
                                               const bf16* __restrict__ Y2,
                                               float* __restrict__ totals) {
  __shared__ bf16 As[128 * 32];
  __shared__ bf16 Bs[128 * 32];
  const int tid = threadIdx.x;
  const int wave = tid >> 6, lane = tid & 63;
  const int wm = (wave >> 1) << 6, wn = (wave & 1) << 6;
  const int lrow = lane & 15, quad = lane >> 4;
  const int m0 = blockIdx.y << 7;
  const int z = blockIdx.z;
  const bf16* A = W2 + ((size_t)z << 17);        // 256*512
  const bf16* B = Y2 + ((size_t)z << 16);        // 128*512

  f32x4 acc[4][4] = {};
  for (int k0 = 0; k0 < 512; k0 += 32) {
#pragma unroll
    for (int c = 0; c < 2; ++c) {
      int rr = ((wave * 2 + c) << 4) + (lane >> 2);
      int cb = stage_c16(lane) << 4;
      int lq = (((wave * 2 + c) << 6) + lane) << 4;
      gload16((const char*)A + (((size_t)(m0 + rr) * 512 + k0) << 1) + cb, (char*)As + lq);
      gload16((const char*)B + (((size_t)rr * 512 + k0) << 1) + cb, (char*)Bs + lq);
    }
    __syncthreads();
    bf16x8 af[4], bfr[4];
#pragma unroll
    for (int i = 0; i < 4; ++i) {
      af[i]  = *(const bf16x8*)(As + frag_off(wm + (i << 4) + lrow, quad));
      bfr[i] = *(const bf16x8*)(Bs + frag_off(wn + (i << 4) + lrow, quad));
    }
#pragma unroll
    for (int mt = 0; mt < 4; ++mt)
#pragma unroll
      for (int nt = 0; nt < 4; ++nt)
        acc[mt][nt] = __builtin_amdgcn_mfma_f32_16x16x32_bf16(af[mt], bfr[nt], acc[mt][nt], 0, 0, 0);
    __syncthreads();
  }

#pragma unroll
  for (int mt = 0; mt < 4; ++mt)
#pragma unroll
    for (int nt = 0; nt < 4; ++nt)
#pragma unroll
      for (int r = 0; r < 4; ++r) {
        int o   = m0 + wm + (mt << 4) + (quad << 2) + r;
        int col = wn + (nt << 4) + lrow;
        int bc = col >> 1, comp = col & 1;
        float self = b2f(B[((size_t)col << 9) + (o << 1)]);
        totals[((((size_t)bc << 13) + (o << 5) + z) << 1) + comp] = acc[mt][nt][r] + self;
      }
}

// In-place exclusive prefix over chunks for each of the 16384 chains.
__global__ void tprefix(float* __restrict__ totals) {
  int id = blockIdx.x * blockDim.x + threadIdx.x;   // (b<<13) + ok
  int b = id >> 13, ok = id & 8191;
  float sr = 0.f, si = 0.f;
  for (int cc = 0; cc < NCHUNK; ++cc) {
    size_t idx = ((((size_t)(b * NCHUNK + cc)) << 13) + ok) << 1;
    float tr = totals[idx], ti = totals[idx + 1];
    totals[idx] = sr; totals[idx + 1] = si;
    sr += tr; si += ti;
  }
}

// ---------------------------------------------------------------------------
// gemm_p: GEMM (x folded) -> twiddle via sincos recurrence -> prefix (register
// scan + independent xor-shuffle quad scan, seeded with inter-chunk carry) ->
// modReLU magnitude -> DPP k-mean -> pooled.
// ---------------------------------------------------------------------------
__global__ __launch_bounds__(256, 3) void gemm_p(
    const bf16* __restrict__ A, const bf16* __restrict__ B, const bf16* __restrict__ x,
    const float* __restrict__ totals, const bf16* __restrict__ mrb, bf16* __restrict__ pooled) {
  __shared__ bf16 As[128 * 32];
  __shared__ bf16 Bs[128 * 32];
  const int tid = threadIdx.x;
  const int wave = tid >> 6, lane = tid & 63;
  const int wm = (wave >> 1) << 6, wn = (wave & 1) << 6;
  const int lrow = lane & 15, quad = lane >> 4;
  const int m0 = blockIdx.y << 7, n0 = blockIdx.x << 7;

  f32x4 acc[4][4] = {};
  for (int k0 = 0; k0 < D_SPEC; k0 += 32) {
#pragma unroll
    for (int c = 0; c < 2; ++c) {
      int rr = ((wave * 2 + c) << 4) + (lane >> 2);
      int cb = stage_c16(lane) << 4;
      int lq = (((wave * 2 + c) << 6) + lane) << 4;
      gload16((const char*)A + (((size_t)(m0 + rr) * D_SPEC + k0) << 1) + cb, (char*)As + lq);
      gload16((const char*)B + (((size_t)(n0 + rr) * D_SPEC + k0) << 1) + cb, (char*)Bs + lq);
    }
    __syncthreads();
    bf16x8 af[4], bfr[4];
#pragma unroll
    for (int i = 0; i < 4; ++i) {
      af[i]  = *(const bf16x8*)(As + frag_off(wm + (i << 4) + lrow, quad));
      bfr[i] = *(const bf16x8*)(Bs + frag_off(wn + (i << 4) + lrow, quad));
    }
#pragma unroll
    for (int mt = 0; mt < 4; ++mt)
#pragma unroll
      for (int nt = 0; nt < 4; ++nt)
        acc[mt][nt] = __builtin_amdgcn_mfma_f32_16x16x32_bf16(af[mt], bfr[nt], acc[mt][nt], 0, 0, 0);
    __syncthreads();
  }

  const int mbase = m0 + wm;                 // 64-row slab == exactly one chunk
  const int b = mbase >> 11;
  const int chunk = (mbase >> 6) & 31;
  const int g0 = (n0 + wn) >> 5;             // even
  const int o = g0 >> 1;                     // lane-uniform

  // fold x into the re-planes
#pragma unroll
  for (int mt = 0; mt < 4; ++mt)
#pragma unroll
    for (int r = 0; r < 4; ++r) {
      int m = mbase + (mt << 4) + (quad << 2) + r;
      float xv = b2f(x[((size_t)m << 8) + o]);
      acc[mt][0][r] += xv;
      acc[mt][2][r] += xv;
    }

  const float c1f = -0.0030679615757712823f;  // -2*pi/2048
  const float norm2 = 0.00048828125f;         // 1/2048
  const float biaso = b2f(mrb[o]);

  float cm[2], smv[2], c1v[2], s1v[2], c16v[2], s16v[2], carR[2], carI[2];
#pragma unroll
  for (int j = 0; j < 2; ++j) {
    const int kk = lrow + (j << 4);
    const int t00 = (mbase & 2047) + (quad << 2);
    __sincosf(c1f * (float)((t00 * kk) & 2047), &smv[j], &cm[j]);
    __sincosf(c1f * (float)kk, &s1v[j], &c1v[j]);
    __sincosf(c1f * (float)((kk << 4) & 2047), &s16v[j], &c16v[j]);
    const int ok = ((g0 + j) << 4) + lrow;
    size_t tb = ((((size_t)(b * NCHUNK + chunk)) << 13) + ok) << 1;
    carR[j] = totals[tb]; carI[j] = totals[tb + 1];
  }

#pragma unroll
  for (int mt = 0; mt < 4; ++mt) {
    float prj[2][4], pij[2][4];
#pragma unroll
    for (int j = 0; j < 2; ++j) {
      float cr_ = cm[j], sr_ = smv[j];
      float vr[4], vi[4];
#pragma unroll
      for (int r = 0; r < 4; ++r) {
        float ur = acc[mt][2 * j][r], ui = acc[mt][2 * j + 1][r];
        vr[r] = cr_ * ur - sr_ * ui;
        vi[r] = cr_ * ui + sr_ * ur;
        if (r < 3) { float cn = cr_ * c1v[j] - sr_ * s1v[j]; sr_ = sr_ * c1v[j] + cr_ * s1v[j]; cr_ = cn; }
      }
      vr[1] += vr[0]; vr[2] += vr[1]; vr[3] += vr[2];
      vi[1] += vi[0]; vi[2] += vi[1]; vi[3] += vi[2];
      float Qr = vr[3], Qi = vi[3];
      float arq = __shfl_xor(Qr, 16, 64), aiq = __shfl_xor(Qi, 16, 64);
      float brq = __shfl_xor(Qr, 32, 64), biq = __shfl_xor(Qi, 32, 64);
      float crq = __shfl_xor(brq, 16, 64), ciq = __shfl_xor(biq, 16, 64);  // Q at quad^3
      float Sr = 0.f, Si = 0.f;
      if (quad & 1) { Sr += arq; Si += aiq; }
      if (quad & 2) { Sr += brq + crq; Si += biq + ciq; }
      float Er = carR[j] + Sr, Ei = carI[j] + Si;
      carR[j] += Qr + arq + brq + crq;
      carI[j] += Qi + aiq + biq + ciq;
#pragma unroll
      for (int r = 0; r < 4; ++r) { prj[j][r] = vr[r] + Er; pij[j][r] = vi[r] + Ei; }
      // advance mt base rotation by delta16
      float cn = cm[j] * c16v[j] - smv[j] * s16v[j];
      smv[j] = smv[j] * c16v[j] + cm[j] * s16v[j];
      cm[j] = cn;
    }
    float red[4];
#pragma unroll
    for (int r = 0; r < 4; ++r) {
      float nm = 0.f;
#pragma unroll
      for (int j = 0; j < 2; ++j) {
        float rr2 = prj[j][r] * prj[j][r] + pij[j][r] * pij[j][r];
        nm += fmaxf(__builtin_amdgcn_sqrtf(norm2 * rr2 + 1e-8f) - biaso, 0.f);
      }
      red[r] = row_sum16(nm);                 // valid at lrow==15
    }
    if (lrow == 15) {
#pragma unroll
      for (int r = 0; r < 4; ++r) {
        int m = mbase + (mt << 4) + (quad << 2) + r;
        pooled[((size_t)m << 8) + o] = __float2bfloat16(red[r] * (1.f / 32.f));
      }
    }
  }
}

// ---------------------------------------------------------------------------
// Plain GEMM for the two dense projections (swizzled LDS).
// EPI 1: +bias, SiLU, store bf16 ; EPI 2: +bias[z], store f32
// ---------------------------------------------------------------------------
template <int EPI>
__global__ __launch_bounds__(256, 2) void gemm_k(
    const bf16* __restrict__ A, const bf16* __restrict__ B, void* __restrict__ Cp,
    const float* __restrict__ bias, int N, int K,
    long long c_bstride, long long b_bstride, int bias_bstride) {
  __shared__ bf16 As[128 * 32];
  __shared__ bf16 Bs[128 * 32];
  const int tid = threadIdx.x;
  const int wave = tid >> 6, lane = tid & 63;
  const int wm = (wave >> 1) << 6, wn = (wave & 1) << 6;
  const int lrow = lane & 15, quad = lane >> 4;
  const int m0 = blockIdx.y << 7, n0 = blockIdx.x << 7;
  const int z = blockIdx.z;
  const bf16* Bz = B + (size_t)z * b_bstride;

  f32x4 acc[4][4] = {};
  for (int k0 = 0; k0 < K; k0 += 32) {
#pragma unroll
    for (int c = 0; c < 2; ++c) {
      int rr = ((wave * 2 + c) << 4) + (lane >> 2);
      int cb = stage_c16(lane) << 4;
      int lq = (((wave * 2 + c) << 6) + lane) << 4;
      gload16((const char*)A  + (((size_t)(m0 + rr) * K + k0) << 1) + cb, (char*)As + lq);
      gload16((const char*)Bz + (((size_t)(n0 + rr) * K + k0) << 1) + cb, (char*)Bs + lq);
    }
    __syncthreads();
    bf16x8 af[4], bfr[4];
#pragma unroll
    for (int i = 0; i < 4; ++i) {
      af[i]  = *(const bf16x8*)(As + frag_off(wm + (i << 4) + lrow, quad));
      bfr[i] = *(const bf16x8*)(Bs + frag_off(wn + (i << 4) + lrow, quad));
    }
#pragma unroll
    for (int mt = 0; mt < 4; ++mt)
#pragma unroll
      for (int nt = 0; nt < 4; ++nt)
        acc[mt][nt] = __builtin_amdgcn_mfma_f32_16x16x32_bf16(af[mt], bfr[nt], acc[mt][nt], 0, 0, 0);
    __syncthreads();
  }

#pragma unroll
  for (int mt = 0; mt < 4; ++mt) {
#pragma unroll
    for (int nt = 0; nt < 4; ++nt) {
#pragma unroll
      for (int r = 0; r < 4; ++r) {
        int gm = m0 + wm + (mt << 4) + (quad << 2) + r;
        int gn = n0 + wn + (nt << 4) + lrow;
        float v = acc[mt][nt][r];
        if (EPI == 1) {
          v += bias[gn];
          v = v / (1.f + __expf(-v));                    // SiLU
          ((bf16*)Cp)[(size_t)gm * N + gn] = __float2bfloat16(v);
        } else {
          v += bias[(size_t)z * bias_bstride + gn];
          ((float*)Cp)[(size_t)z * c_bstride + (size_t)gm * N + gn] = v;
        }
      }
    }
  }
}

// ---------------------------------------------------------------------------
extern "C" void kernel_launch(void* const* d_in, const int* in_sizes, int n_in,
                              void* d_out, int out_size, void* d_ws, size_t ws_size,
                              hipStream_t stream) {
  const bf16* x        = (const bf16*)d_in[0];
  const bf16* conv_w   = (const bf16*)d_in[1];
  const bf16* mrb      = (const bf16*)d_in[2];
  const float* w_shared = (const float*)d_in[3];
  const float* b_shared = (const float*)d_in[4];
  const float* layer_w  = (const float*)d_in[5];
  const float* layer_b  = (const float*)d_in[6];
  float* out = (float*)d_out;

  char* ws = (char*)d_ws;
  bf16* Bmat    = (bf16*)(ws);                // 8,388,608
  bf16* W2      = (bf16*)(ws + 8388608);      // 8,388,608   -> 16,777,216
  bf16* Y2      = (bf16*)(ws + 16777216);     // 4,194,304   -> 20,971,520
  float2* twtab = (float2*)(ws + 20971520);   // 524,288     -> 21,495,808
  float* totals = (float*)(ws + 21495808);    // 4,194,304   -> 25,690,112
  bf16* pooled  = (bf16*)(ws + 25690112);     // 2,097,152   -> 27,787,264
  bf16* wsb     = (bf16*)(ws + 27787264);     // 393,216     -> 28,180,480
  bf16* hidden  = (bf16*)(ws + 28180480);     // 6,291,456   -> 34,471,936
  bf16* lwb     = (bf16*)(ws + 34471936);     // 9,437,184   -> 43,909,120

  prep<<<2048, 256, 0, stream>>>(conv_w, w_shared, layer_w, Bmat, W2, wsb, lwb, twtab);

  // chunk totals via the small algebraic path (replaces the 68.7 GF gemm_t pass)
  ybuild<<<128, 256, 0, stream>>>(x, twtab, Y2);
  wtot<<<dim3(1, 2, K_MAX), 256, 0, stream>>>(W2, Y2, totals);
  tprefix<<<64, 256, 0, stream>>>(totals);

  // single big GEMM pass: recompute u, prefix, modReLU, pool
  gemm_p<<<dim3(NU / 128, MTOT / 128, 1), 256, 0, stream>>>(x, Bmat, x, totals, mrb, pooled);

  // hidden = silu(pooled @ w_shared^T + b_shared)
  gemm_k<1><<<dim3(D_MODEL / 128, MTOT / 128, 1), 256, 0, stream>>>(
      pooled, wsb, hidden, b_shared, D_MODEL, D_SPEC, 0, 0, 0);

  // cond[l] = hidden @ layer_w[l]^T + layer_b[l]
  gemm_k<2><<<dim3(NCOND / 128, MTOT / 128, N_LAYERS), 256, 0, stream>>>(
      hidden, lwb, out, layer_b, NCOND, D_MODEL,
      (long long)MTOT * NCOND, (long long)NCOND * D_MODEL, NCOND);
}

// Round 8
// 297.657 us; speedup vs baseline: 1.1420x; 1.0932x over previous
//
#include <hip/hip_runtime.h>
#include <hip/hip_bf16.h>

typedef __hip_bfloat16 bf16;
typedef __attribute__((ext_vector_type(8))) short bf16x8;  // 8 bf16 in 4 VGPRs
typedef __attribute__((ext_vector_type(4))) float f32x4;

#define SEQ_LEN 2048
#define K_MAX   32
#define D_SPEC  256
#define D_MODEL 768
#define N_LAYERS 4
#define BATCH   2
#define MTOT    (BATCH * SEQ_LEN)       // 4096 rows (b*2048+t)
#define NU      (D_SPEC * K_MAX * 2)    // 16384 cols; n = (ok>>4)*32 + ri*16 + (ok&15)
#define NCOND   (2 * D_MODEL)           // 1536
#define NCHUNK  32

__device__ inline float b2f(bf16 h) { return __bfloat162float(h); }

__device__ inline void gload16(const void* gp, void* lp) {
  __builtin_amdgcn_global_load_lds((const __attribute__((address_space(1))) void*)gp,
                                   (__attribute__((address_space(3))) void*)lp, 16, 0, 0);
}

// LDS XOR swizzle (neutral but harmless; staging-side conflicts are structural).
__device__ inline int stage_c16(int lane) { return ((lane & 3) ^ ((lane >> 2) & 3) ^ ((lane >> 4) & 3)); }
__device__ inline int frag_off(int R, int q) {
  return (R << 5) + (((q ^ (R & 3) ^ ((R >> 2) & 3)) & 3) << 3);
}

// Full-rate DPP sum over each 16-lane row; result valid in lane 15 of each row.
__device__ inline float row_sum16(float v) {
  v += __int_as_float(__builtin_amdgcn_update_dpp(0, __float_as_int(v), 0x111, 0xF, 0xF, true)); // row_shr:1
  v += __int_as_float(__builtin_amdgcn_update_dpp(0, __float_as_int(v), 0x112, 0xF, 0xF, true)); // row_shr:2
  v += __int_as_float(__builtin_amdgcn_update_dpp(0, __float_as_int(v), 0x114, 0xF, 0xF, true)); // row_shr:4
  v += __int_as_float(__builtin_amdgcn_update_dpp(0, __float_as_int(v), 0x118, 0xF, 0xF, true)); // row_shr:8
  return v;
}

// ---------------------------------------------------------------------------
// prep_t: one block per o. Contiguous 16B reads of conv_w[o] -> LDS transpose ->
// fully coalesced writes of Bmat (gemm_p B^T layout) and W2 (wtot A layout).
// ---------------------------------------------------------------------------
__global__ __launch_bounds__(256) void prep_t(const bf16* __restrict__ conv_w,
                                              bf16* __restrict__ Bmat, bf16* __restrict__ W2) {
  __shared__ bf16 L[256][66];        // [i][kc], pad 66 -> conflict-free column reads
  const int o = blockIdx.x;
  const int tid = threadIdx.x;
  const bf16* src = conv_w + (size_t)o * 16384;
#pragma unroll
  for (int it = 0; it < 8; ++it) {
    int v = tid + (it << 8);         // 16B granule index, 2048 total
    int e = v << 3;                  // element base
    int i = e >> 6, kc = e & 63;
    uint4 d = *(const uint4*)(src + e);      // coalesced 16B
    *(unsigned*)&L[i][kc]     = d.x;         // 4B-aligned LDS writes
    *(unsigned*)&L[i][kc + 2] = d.y;
    *(unsigned*)&L[i][kc + 4] = d.z;
    *(unsigned*)&L[i][kc + 6] = d.w;
  }
  __syncthreads();
  // Bmat[n][i], n = (2o + (kc>>5))*32 + (kc&1)*16 + ((kc>>1)&15)
#pragma unroll
  for (int kc = 0; kc < 64; ++kc) {
    int n = ((o << 1) + (kc >> 5)) * 32 + ((kc & 1) << 4) + ((kc >> 1) & 15);
    Bmat[((size_t)n << 8) + tid] = L[tid][kc];   // coalesced 512B row
  }
  // W2[k][o][i2] = L[i2>>1][(k<<1)+(i2&1)]
#pragma unroll
  for (int k = 0; k < 32; ++k) {
#pragma unroll
    for (int h = 0; h < 2; ++h) {
      int i2 = (h << 8) + tid;
      W2[((size_t)k << 17) + (o << 9) + i2] = L[i2 >> 1][(k << 1) + (i2 & 1)];
    }
  }
}

// prep2: coalesced bf16 casts of w_shared / layer_w.
__global__ void prep2(const float* __restrict__ w_shared, const float* __restrict__ layer_w,
                      bf16* __restrict__ wsb, bf16* __restrict__ lwb) {
  int idx = blockIdx.x * blockDim.x + threadIdx.x;
  int stride = gridDim.x * blockDim.x;
  for (int j = idx; j < D_MODEL * D_SPEC; j += stride) wsb[j] = __float2bfloat16(w_shared[j]);
  for (int j = idx; j < N_LAYERS * NCOND * D_MODEL; j += stride) lwb[j] = __float2bfloat16(layer_w[j]);
}

// ---------------------------------------------------------------------------
// ybuild: Y[b,c,k,i] = sum_{t in chunk} tw(t,k)*x[b,t,i], twiddles via rotation
// recurrence in registers. Grid 2048 = (bc 64) x (k 32); threads = i.
// Y2 layout (wtot B^T): row=(k<<7)+(bc<<1)+comp, 512 cols (2i interleave);
// comp=r: (yc,-ys), comp=i: (ys,yc).
// ---------------------------------------------------------------------------
__global__ __launch_bounds__(256) void ybuild(const bf16* __restrict__ x, bf16* __restrict__ Y2) {
  const int bid = blockIdx.x;
  const int bc = bid >> 5, k = bid & 31;
  const int b = bc >> 5, c = bc & 31;
  const int t0 = c << 6;
  const int i = threadIdx.x;
  const float c1f = -0.0030679615757712823f;  // -2*pi/2048
  float cs, sn, cd, sd;
  __sincosf(c1f * (float)((t0 * k) & 2047), &sn, &cs);
  __sincosf(c1f * (float)k, &sd, &cd);
  float aC = 0.f, aS = 0.f;
  const bf16* xp = x + (((size_t)((b << 11) + t0)) << 8) + i;
#pragma unroll 8
  for (int t = 0; t < 64; ++t) {
    float xv = b2f(*xp); xp += D_SPEC;
    aC += cs * xv; aS += sn * xv;
    float cn = cs * cd - sn * sd; sn = sn * cd + cs * sd; cs = cn;
  }
  __hip_bfloat162 p0, p1;
  p0.x = __float2bfloat16(aC);  p0.y = __float2bfloat16(-aS);
  p1.x = __float2bfloat16(aS);  p1.y = __float2bfloat16(aC);
  *(__hip_bfloat162*)(Y2 + (((size_t)(k << 7) + (bc << 1)) << 9) + (i << 1)) = p0;
  *(__hip_bfloat162*)(Y2 + (((size_t)(k << 7) + (bc << 1) + 1) << 9) + (i << 1)) = p1;
}

// ---------------------------------------------------------------------------
// wtot: per-k complex GEMM totals[bc,o,k] = W[k] (256o x 512) @ Y2[k]^T (128col x 512)
// + self-term Y[bc,k,o]. Grid (1, 2, 32).
// ---------------------------------------------------------------------------
__global__ __launch_bounds__(256, 2) void wtot(const bf16* __restrict__ W2,
                                               const bf16* __restrict__ Y2,
                                               float* __restrict__ totals) {
  __shared__ bf16 As[128 * 32];
  __shared__ bf16 Bs[128 * 32];
  const int tid = threadIdx.x;
  const int wave = tid >> 6, lane = tid & 63;
  const int wm = (wave >> 1) << 6, wn = (wave & 1) << 6;
  const int lrow = lane & 15, quad = lane >> 4;
  const int m0 = blockIdx.y << 7;
  const int z = blockIdx.z;
  const bf16* A = W2 + ((size_t)z << 17);        // 256*512
  const bf16* B = Y2 + ((size_t)z << 16);        // 128*512

  f32x4 acc[4][4] = {};
  for (int k0 = 0; k0 < 512; k0 += 32) {
#pragma unroll
    for (int c = 0; c < 2; ++c) {
      int rr = ((wave * 2 + c) << 4) + (lane >> 2);
      int cb = stage_c16(lane) << 4;
      int lq = (((wave * 2 + c) << 6) + lane) << 4;
      gload16((const char*)A + (((size_t)(m0 + rr) * 512 + k0) << 1) + cb, (char*)As + lq);
      gload16((const char*)B + (((size_t)rr * 512 + k0) << 1) + cb, (char*)Bs + lq);
    }
    __syncthreads();
    bf16x8 af[4], bfr[4];
#pragma unroll
    for (int i = 0; i < 4; ++i) {
      af[i]  = *(const bf16x8*)(As + frag_off(wm + (i << 4) + lrow, quad));
      bfr[i] = *(const bf16x8*)(Bs + frag_off(wn + (i << 4) + lrow, quad));
    }
#pragma unroll
    for (int mt = 0; mt < 4; ++mt)
#pragma unroll
      for (int nt = 0; nt < 4; ++nt)
        acc[mt][nt] = __builtin_amdgcn_mfma_f32_16x16x32_bf16(af[mt], bfr[nt], acc[mt][nt], 0, 0, 0);
    __syncthreads();
  }

#pragma unroll
  for (int mt = 0; mt < 4; ++mt)
#pragma unroll
    for (int nt = 0; nt < 4; ++nt)
#pragma unroll
      for (int r = 0; r < 4; ++r) {
        int o   = m0 + wm + (mt << 4) + (quad << 2) + r;
        int col = wn + (nt << 4) + lrow;
        int bc = col >> 1, comp = col & 1;
        float self = b2f(B[((size_t)col << 9) + (o << 1)]);
        totals[((((size_t)bc << 13) + (o << 5) + z) << 1) + comp] = acc[mt][nt][r] + self;
      }
}

// In-place exclusive prefix over chunks for each of the 16384 chains.
__global__ void tprefix(float* __restrict__ totals) {
  int id = blockIdx.x * blockDim.x + threadIdx.x;   // (b<<13) + ok
  int b = id >> 13, ok = id & 8191;
  float sr = 0.f, si = 0.f;
  for (int cc = 0; cc < NCHUNK; ++cc) {
    size_t idx = ((((size_t)(b * NCHUNK + cc)) << 13) + ok) << 1;
    float tr = totals[idx], ti = totals[idx + 1];
    totals[idx] = sr; totals[idx + 1] = si;
    sr += tr; si += ti;
  }
}

// ---------------------------------------------------------------------------
// gemm_p: GEMM (x folded) -> twiddle via sincos recurrence -> prefix (register
// scan + independent xor-shuffle quad scan, seeded with inter-chunk carry) ->
// modReLU magnitude -> DPP k-mean -> pooled.
// ---------------------------------------------------------------------------
__global__ __launch_bounds__(256, 3) void gemm_p(
    const bf16* __restrict__ A, const bf16* __restrict__ B, const bf16* __restrict__ x,
    const float* __restrict__ totals, const bf16* __restrict__ mrb, bf16* __restrict__ pooled) {
  __shared__ bf16 As[128 * 32];
  __shared__ bf16 Bs[128 * 32];
  const int tid = threadIdx.x;
  const int wave = tid >> 6, lane = tid & 63;
  const int wm = (wave >> 1) << 6, wn = (wave & 1) << 6;
  const int lrow = lane & 15, quad = lane >> 4;
  const int m0 = blockIdx.y << 7, n0 = blockIdx.x << 7;

  f32x4 acc[4][4] = {};
  for (int k0 = 0; k0 < D_SPEC; k0 += 32) {
#pragma unroll
    for (int c = 0; c < 2; ++c) {
      int rr = ((wave * 2 + c) << 4) + (lane >> 2);
      int cb = stage_c16(lane) << 4;
      int lq = (((wave * 2 + c) << 6) + lane) << 4;
      gload16((const char*)A + (((size_t)(m0 + rr) * D_SPEC + k0) << 1) + cb, (char*)As + lq);
      gload16((const char*)B + (((size_t)(n0 + rr) * D_SPEC + k0) << 1) + cb, (char*)Bs + lq);
    }
    __syncthreads();
    bf16x8 af[4], bfr[4];
#pragma unroll
    for (int i = 0; i < 4; ++i) {
      af[i]  = *(const bf16x8*)(As + frag_off(wm + (i << 4) + lrow, quad));
      bfr[i] = *(const bf16x8*)(Bs + frag_off(wn + (i << 4) + lrow, quad));
    }
#pragma unroll
    for (int mt = 0; mt < 4; ++mt)
#pragma unroll
      for (int nt = 0; nt < 4; ++nt)
        acc[mt][nt] = __builtin_amdgcn_mfma_f32_16x16x32_bf16(af[mt], bfr[nt], acc[mt][nt], 0, 0, 0);
    __syncthreads();
  }

  const int mbase = m0 + wm;                 // 64-row slab == exactly one chunk
  const int b = mbase >> 11;
  const int chunk = (mbase >> 6) & 31;
  const int g0 = (n0 + wn) >> 5;             // even
  const int o = g0 >> 1;                     // lane-uniform

  // fold x into the re-planes
#pragma unroll
  for (int mt = 0; mt < 4; ++mt)
#pragma unroll
    for (int r = 0; r < 4; ++r) {
      int m = mbase + (mt << 4) + (quad << 2) + r;
      float xv = b2f(x[((size_t)m << 8) + o]);
      acc[mt][0][r] += xv;
      acc[mt][2][r] += xv;
    }

  const float c1f = -0.0030679615757712823f;  // -2*pi/2048
  const float norm2 = 0.00048828125f;         // 1/2048
  const float biaso = b2f(mrb[o]);

  float cm[2], smv[2], c1v[2], s1v[2], c16v[2], s16v[2], carR[2], carI[2];
#pragma unroll
  for (int j = 0; j < 2; ++j) {
    const int kk = lrow + (j << 4);
    const int t00 = (mbase & 2047) + (quad << 2);
    __sincosf(c1f * (float)((t00 * kk) & 2047), &smv[j], &cm[j]);
    __sincosf(c1f * (float)kk, &s1v[j], &c1v[j]);
    __sincosf(c1f * (float)((kk << 4) & 2047), &s16v[j], &c16v[j]);
    const int ok = ((g0 + j) << 4) + lrow;
    size_t tb = ((((size_t)(b * NCHUNK + chunk)) << 13) + ok) << 1;
    carR[j] = totals[tb]; carI[j] = totals[tb + 1];
  }

#pragma unroll
  for (int mt = 0; mt < 4; ++mt) {
    float prj[2][4], pij[2][4];
#pragma unroll
    for (int j = 0; j < 2; ++j) {
      float cr_ = cm[j], sr_ = smv[j];
      float vr[4], vi[4];
#pragma unroll
      for (int r = 0; r < 4; ++r) {
        float ur = acc[mt][2 * j][r], ui = acc[mt][2 * j + 1][r];
        vr[r] = cr_ * ur - sr_ * ui;
        vi[r] = cr_ * ui + sr_ * ur;
        if (r < 3) { float cn = cr_ * c1v[j] - sr_ * s1v[j]; sr_ = sr_ * c1v[j] + cr_ * s1v[j]; cr_ = cn; }
      }
      vr[1] += vr[0]; vr[2] += vr[1]; vr[3] += vr[2];
      vi[1] += vi[0]; vi[2] += vi[1]; vi[3] += vi[2];
      float Qr = vr[3], Qi = vi[3];
      float arq = __shfl_xor(Qr, 16, 64), aiq = __shfl_xor(Qi, 16, 64);
      float brq = __shfl_xor(Qr, 32, 64), biq = __shfl_xor(Qi, 32, 64);
      float crq = __shfl_xor(brq, 16, 64), ciq = __shfl_xor(biq, 16, 64);  // Q at quad^3
      float Sr = 0.f, Si = 0.f;
      if (quad & 1) { Sr += arq; Si += aiq; }
      if (quad & 2) { Sr += brq + crq; Si += biq + ciq; }
      float Er = carR[j] + Sr, Ei = carI[j] + Si;
      carR[j] += Qr + arq + brq + crq;
      carI[j] += Qi + aiq + biq + ciq;
#pragma unroll
      for (int r = 0; r < 4; ++r) { prj[j][r] = vr[r] + Er; pij[j][r] = vi[r] + Ei; }
      // advance mt base rotation by delta16
      float cn = cm[j] * c16v[j] - smv[j] * s16v[j];
      smv[j] = smv[j] * c16v[j] + cm[j] * s16v[j];
      cm[j] = cn;
    }
    float red[4];
#pragma unroll
    for (int r = 0; r < 4; ++r) {
      float nm = 0.f;
#pragma unroll
      for (int j = 0; j < 2; ++j) {
        float rr2 = prj[j][r] * prj[j][r] + pij[j][r] * pij[j][r];
        nm += fmaxf(__builtin_amdgcn_sqrtf(norm2 * rr2 + 1e-8f) - biaso, 0.f);
      }
      red[r] = row_sum16(nm);                 // valid at lrow==15
    }
    if (lrow == 15) {
#pragma unroll
      for (int r = 0; r < 4; ++r) {
        int m = mbase + (mt << 4) + (quad << 2) + r;
        pooled[((size_t)m << 8) + o] = __float2bfloat16(red[r] * (1.f / 32.f));
      }
    }
  }
}

// ---------------------------------------------------------------------------
// Plain GEMM for the two dense projections (swizzled LDS).
// EPI 1: +bias, SiLU, store bf16 ; EPI 2: +bias[z], store f32
// ---------------------------------------------------------------------------
template <int EPI>
__global__ __launch_bounds__(256, 2) void gemm_k(
    const bf16* __restrict__ A, const bf16* __restrict__ B, void* __restrict__ Cp,
    const float* __restrict__ bias, int N, int K,
    long long c_bstride, long long b_bstride, int bias_bstride) {
  __shared__ bf16 As[128 * 32];
  __shared__ bf16 Bs[128 * 32];
  const int tid = threadIdx.x;
  const int wave = tid >> 6, lane = tid & 63;
  const int wm = (wave >> 1) << 6, wn = (wave & 1) << 6;
  const int lrow = lane & 15, quad = lane >> 4;
  const int m0 = blockIdx.y << 7, n0 = blockIdx.x << 7;
  const int z = blockIdx.z;
  const bf16* Bz = B + (size_t)z * b_bstride;

  f32x4 acc[4][4] = {};
  for (int k0 = 0; k0 < K; k0 += 32) {
#pragma unroll
    for (int c = 0; c < 2; ++c) {
      int rr = ((wave * 2 + c) << 4) + (lane >> 2);
      int cb = stage_c16(lane) << 4;
      int lq = (((wave * 2 + c) << 6) + lane) << 4;
      gload16((const char*)A  + (((size_t)(m0 + rr) * K + k0) << 1) + cb, (char*)As + lq);
      gload16((const char*)Bz + (((size_t)(n0 + rr) * K + k0) << 1) + cb, (char*)Bs + lq);
    }
    __syncthreads();
    bf16x8 af[4], bfr[4];
#pragma unroll
    for (int i = 0; i < 4; ++i) {
      af[i]  = *(const bf16x8*)(As + frag_off(wm + (i << 4) + lrow, quad));
      bfr[i] = *(const bf16x8*)(Bs + frag_off(wn + (i << 4) + lrow, quad));
    }
#pragma unroll
    for (int mt = 0; mt < 4; ++mt)
#pragma unroll
      for (int nt = 0; nt < 4; ++nt)
        acc[mt][nt] = __builtin_amdgcn_mfma_f32_16x16x32_bf16(af[mt], bfr[nt], acc[mt][nt], 0, 0, 0);
    __syncthreads();
  }

#pragma unroll
  for (int mt = 0; mt < 4; ++mt) {
#pragma unroll
    for (int nt = 0; nt < 4; ++nt) {
#pragma unroll
      for (int r = 0; r < 4; ++r) {
        int gm = m0 + wm + (mt << 4) + (quad << 2) + r;
        int gn = n0 + wn + (nt << 4) + lrow;
        float v = acc[mt][nt][r];
        if (EPI == 1) {
          v += bias[gn];
          v = v / (1.f + __expf(-v));                    // SiLU
          ((bf16*)Cp)[(size_t)gm * N + gn] = __float2bfloat16(v);
        } else {
          v += bias[(size_t)z * bias_bstride + gn];
          ((float*)Cp)[(size_t)z * c_bstride + (size_t)gm * N + gn] = v;
        }
      }
    }
  }
}

// ---------------------------------------------------------------------------
extern "C" void kernel_launch(void* const* d_in, const int* in_sizes, int n_in,
                              void* d_out, int out_size, void* d_ws, size_t ws_size,
                              hipStream_t stream) {
  const bf16* x        = (const bf16*)d_in[0];
  const bf16* conv_w   = (const bf16*)d_in[1];
  const bf16* mrb      = (const bf16*)d_in[2];
  const float* w_shared = (const float*)d_in[3];
  const float* b_shared = (const float*)d_in[4];
  const float* layer_w  = (const float*)d_in[5];
  const float* layer_b  = (const float*)d_in[6];
  float* out = (float*)d_out;

  char* ws = (char*)d_ws;
  bf16* Bmat    = (bf16*)(ws);                // 8,388,608
  bf16* W2      = (bf16*)(ws + 8388608);      // 8,388,608   -> 16,777,216
  bf16* Y2      = (bf16*)(ws + 16777216);     // 4,194,304   -> 20,971,520
  float* totals = (float*)(ws + 20971520);    // 4,194,304   -> 25,165,824
  bf16* pooled  = (bf16*)(ws + 25165824);     // 2,097,152   -> 27,262,976
  bf16* wsb     = (bf16*)(ws + 27262976);     // 393,216     -> 27,656,192
  bf16* hidden  = (bf16*)(ws + 27656192);     // 6,291,456   -> 33,947,648
  bf16* lwb     = (bf16*)(ws + 33947648);     // 9,437,184   -> 43,384,832

  prep_t<<<256, 256, 0, stream>>>(conv_w, Bmat, W2);
  prep2<<<1024, 256, 0, stream>>>(w_shared, layer_w, wsb, lwb);

  // chunk totals via the small algebraic path
  ybuild<<<2048, 256, 0, stream>>>(x, Y2);
  wtot<<<dim3(1, 2, K_MAX), 256, 0, stream>>>(W2, Y2, totals);
  tprefix<<<64, 256, 0, stream>>>(totals);

  // single big GEMM pass: recompute u, prefix, modReLU, pool
  gemm_p<<<dim3(NU / 128, MTOT / 128, 1), 256, 0, stream>>>(x, Bmat, x, totals, mrb, pooled);

  // hidden = silu(pooled @ w_shared^T + b_shared)
  gemm_k<1><<<dim3(D_MODEL / 128, MTOT / 128, 1), 256, 0, stream>>>(
      pooled, wsb, hidden, b_shared, D_MODEL, D_SPEC, 0, 0, 0);

  // cond[l] = hidden @ layer_w[l]^T + layer_b[l]
  gemm_k<2><<<dim3(NCOND / 128, MTOT / 128, N_LAYERS), 256, 0, stream>>>(
      hidden, lwb, out, layer_b, NCOND, D_MODEL,
      (long long)MTOT * NCOND, (long long)NCOND * D_MODEL, NCOND);
}